// Round 8
// baseline (207.449 us; speedup 1.0000x reference)
//
#include <hip/hip_runtime.h>
#include <cmath>

// Problem constants
#define M_B   8
#define LQ    256
#define N_B   64
#define LR    512
#define COND  64
#define PRED  32
#define DH    128
#define QN    193      // LQ-COND+1
#define KN    417      // (LR-PRED)-COND+1
#define QPAD  256      // per-m padded q rows (qfeat/q_scale layout only)
#define KPAD  448      // padded kpos (14 chunks of 32)
#define QROWS 1544     // M_B*QN packed q rows (R7)
#define QGRPS 49       // ceil(QROWS/32)

typedef _Float16 half8 __attribute__((ext_vector_type(8)));
typedef float f32x16 __attribute__((ext_vector_type(16)));

__device__ __forceinline__ f32x16 mfma_f16(half8 a, half8 b, f32x16 c) {
    return __builtin_amdgcn_mfma_f32_32x32x16_f16(a, b, c, 0, 0, 0);
}
__device__ __forceinline__ f32x16 zero16() {
    f32x16 z;
    #pragma unroll
    for (int i = 0; i < 16; i++) z[i] = 0.f;
    return z;
}

#define GLOAD_LDS16(g, l) __builtin_amdgcn_global_load_lds( \
    (const __attribute__((address_space(1))) void*)(g), \
    (__attribute__((address_space(3))) void*)(l), 16, 0, 0)

// Force a float to live in a VGPR (blocks LDS-rematerialization of loads).
#define PIN_V(x) asm volatile("" : "+v"(x))

// ---------------- KA: fused feature kernel ----------------
// R6: scan-free (relative window sums, translation-invariant).
// R7: qg emitted in PACKED row layout (prow = m*QN + qpos, 49 groups of 32).
// R8: ghost-frag memset dropped — ghost A-rows can't contaminate real MFMA
// output rows (row-independence), ghost best-slots are write-guarded, reads
// stay in-bounds. One fewer dispatch.
__launch_bounds__(256, 2)
__global__ void kA_feat(const float* __restrict__ query, const float* __restrict__ ref,
                        const float* __restrict__ qw, const float* __restrict__ qb,
                        const float* __restrict__ kw, const float* __restrict__ kb,
                        const float* __restrict__ vw, const float* __restrict__ vb,
                        float* __restrict__ q_scale, float* __restrict__ qfeat,
                        _Float16* __restrict__ qg,
                        _Float16* __restrict__ kg, float* __restrict__ vfeat) {
    __shared__ float x[512];
    __shared__ float buf[128 * 65];
    const int t = threadIdx.x;
    const int kl = t & 63;
    const int hq = __builtin_amdgcn_readfirstlane(t >> 6);

    if (blockIdx.x < 448) {
        // ================= K/V branch =================
        const int n = blockIdx.x / 7, chunk = blockIdx.x % 7;
        x[t] = ref[n * 512 + t];
        x[t + 256] = ref[n * 512 + t + 256];
        __syncthreads();

        const int kp = chunk * 64 + kl;
        const bool vkp = kp < KN;
        // relative window sums: csw[j] = sum ref[kp+1 .. kp+j]  (csw[0] = 0)
        float csw[64];
        float run = 0.f, mn = 0.f, mx = 0.f;
        csw[0] = 0.f;
        #pragma unroll
        for (int j = 1; j < 64; j++) {
            run += x[kp + j];                // kp+63 <= 510, in range
            csw[j] = run;
            mn = fminf(mn, run);
            mx = fmaxf(mx, run);
        }
        float scv = mx - mn; if (scv == 0.f) scv = 1.f;
        const float inv = 1.f / scv;
        #pragma unroll
        for (int j = 0; j < 64; j++) { csw[j] -= mn; PIN_V(csw[j]); }

        // ---- k features ----
        for (int hh = 0; hh < 32; hh++) {
            const int h = hq * 32 + hh;      // wave-uniform -> s_load weights
            const float* wrow = kw + h * 64;
            float a0 = 0.f, a1 = 0.f, a2 = 0.f, a3 = 0.f;
            #pragma unroll
            for (int j = 0; j < 64; j += 4) {
                a0 = fmaf(wrow[j],     csw[j],     a0);
                a1 = fmaf(wrow[j + 1], csw[j + 1], a1);
                a2 = fmaf(wrow[j + 2], csw[j + 2], a2);
                a3 = fmaf(wrow[j + 3], csw[j + 3], a3);
            }
            float kraw = (a0 + a1) + (a2 + a3);
            float kval = vkp ? kraw * inv + kb[h] : 0.f;
            buf[h * 65 + (kl ^ (h >> 3))] = kval;
        }
        __syncthreads();
        // emit kg: 64 kp x 32 granules (16 hi + 16 lo), swizzled by kp&31
        {
            const size_t nb = ((size_t)n * KPAD + chunk * 64) * 256;
            #pragma unroll
            for (int r = 0; r < 8; r++) {
                int task = r * 256 + t;
                int kp_l = task >> 5, g = task & 31;
                int cb = g & 15, lo = g >> 4;
                half8 hv;
                #pragma unroll
                for (int jj = 0; jj < 8; jj++) {
                    float v = buf[(cb * 8 + jj) * 65 + (kp_l ^ cb)];
                    _Float16 hi = (_Float16)v;
                    hv[jj] = lo ? (_Float16)((v - (float)hi) * 1024.0f) : hi;
                }
                *(half8*)&kg[nb + (size_t)kp_l * 256 + ((size_t)(g ^ (kp_l & 31)) << 3)] = hv;
            }
        }
        __syncthreads();
        // ---- v features ----
        float refw[32];
        #pragma unroll
        for (int j = 0; j < 32; j++) {
            int ri = 64 + kp + j;
            refw[j] = (ri < 512) ? x[ri] : 0.f;
            PIN_V(refw[j]);
        }
        for (int hh = 0; hh < 32; hh++) {
            const int h = hq * 32 + hh;
            const float* vrow = vw + h * 32;
            float b0 = 0.f, b1 = 0.f;
            #pragma unroll
            for (int j = 0; j < 32; j += 2) {
                b0 = fmaf(vrow[j],     refw[j],     b0);
                b1 = fmaf(vrow[j + 1], refw[j + 1], b1);
            }
            float vval = vkp ? (b0 + b1) * inv + vb[h] : 0.f;
            buf[h * 65 + (kl ^ (h >> 3))] = vval;
        }
        __syncthreads();
        {
            const size_t vb0 = ((size_t)n * KPAD + chunk * 64) * 128;
            #pragma unroll
            for (int r = 0; r < 8; r++) {
                int idx = r * 256 + t;
                int kp_l = idx >> 5, c4 = idx & 31;
                float4 o;
                o.x = buf[(c4 * 4 + 0) * 65 + (kp_l ^ ((c4 * 4 + 0) >> 3))];
                o.y = buf[(c4 * 4 + 1) * 65 + (kp_l ^ ((c4 * 4 + 1) >> 3))];
                o.z = buf[(c4 * 4 + 2) * 65 + (kp_l ^ ((c4 * 4 + 2) >> 3))];
                o.w = buf[(c4 * 4 + 3) * 65 + (kp_l ^ ((c4 * 4 + 3) >> 3))];
                *(float4*)&vfeat[vb0 + (size_t)kp_l * 128 + c4 * 4] = o;
            }
        }
    } else {
        // ================= Q branch =================
        const int id = blockIdx.x - 448;
        const int m = id >> 2, qc = id & 3;
        x[t] = query[m * 256 + t];
        __syncthreads();

        const int qpos = qc * 64 + kl;
        const bool vq = qpos < QN;
        const int base = vq ? qpos : (QN - 1);
        float csw[64];
        float run = 0.f, mn = 0.f, mx = 0.f;
        csw[0] = 0.f;
        #pragma unroll
        for (int j = 1; j < 64; j++) {
            run += x[base + j];              // base+63 <= 255, in range
            csw[j] = run;
            mn = fminf(mn, run);
            mx = fmaxf(mx, run);
        }
        float sc = mx - mn; if (sc == 0.f) sc = 1.f;
        const float inv = 1.f / sc;
        if (t < 64) q_scale[m * QPAD + qpos] = vq ? sc : 1.f;
        #pragma unroll
        for (int j = 0; j < 64; j++) { csw[j] -= mn; PIN_V(csw[j]); }

        for (int hh = 0; hh < 32; hh++) {
            const int h = hq * 32 + hh;      // wave-uniform -> s_load weights
            const float* wrow = qw + h * 64;
            float a0 = 0.f, a1 = 0.f, a2 = 0.f, a3 = 0.f;
            #pragma unroll
            for (int j = 0; j < 64; j += 4) {
                a0 = fmaf(wrow[j],     csw[j],     a0);
                a1 = fmaf(wrow[j + 1], csw[j + 1], a1);
                a2 = fmaf(wrow[j + 2], csw[j + 2], a2);
                a3 = fmaf(wrow[j + 3], csw[j + 3], a3);
            }
            float raw = (a0 + a1) + (a2 + a3);
            float val = vq ? raw * inv + qb[h] : 0.f;
            buf[h * 65 + (kl ^ (h >> 3))] = val;
        }
        __syncthreads();
        // emit qfeat (coalesced float4, QPAD layout — unchanged)
        const size_t qb0 = ((size_t)m * QPAD + qc * 64) * 128;
        #pragma unroll
        for (int r = 0; r < 8; r++) {
            int idx = r * 256 + t;
            int qp_l = idx >> 5, c4 = idx & 31;
            float4 o;
            o.x = buf[(c4 * 4 + 0) * 65 + (qp_l ^ ((c4 * 4 + 0) >> 3))];
            o.y = buf[(c4 * 4 + 1) * 65 + (qp_l ^ ((c4 * 4 + 1) >> 3))];
            o.z = buf[(c4 * 4 + 2) * 65 + (qp_l ^ ((c4 * 4 + 2) >> 3))];
            o.w = buf[(c4 * 4 + 3) * 65 + (qp_l ^ ((c4 * 4 + 3) >> 3))];
            *(float4*)&qfeat[qb0 + (size_t)qp_l * 128 + c4 * 4] = o;
        }
        // emit qg frag-major hi/lo, PACKED rows: prow = m*QN + qpos
        #pragma unroll
        for (int r = 0; r < 8; r++) {
            int idx = r * 256 + t;
            int qp_l = idx >> 5, g = idx & 31;
            int c = g >> 2, kh = (g >> 1) & 1, lo = g & 1;
            int qp2 = qc * 64 + qp_l;
            if (qp2 < QN) {
                half8 hv;
                #pragma unroll
                for (int jj = 0; jj < 8; jj++) {
                    int h = c * 16 + kh * 8 + jj;
                    float v = buf[h * 65 + (qp_l ^ (h >> 3))];
                    _Float16 hi = (_Float16)v;
                    hv[jj] = lo ? (_Float16)((v - (float)hi) * 1024.0f) : hi;
                }
                int prow = m * QN + qp2;
                int grp = prow >> 5;
                size_t fb = (size_t)(grp * 16 + c * 2 + lo);
                *(half8*)&qg[fb * 512 + (size_t)(kh * 32 + (prow & 31)) * 8] = hv;
            }
        }
    }
}

// ---------------- K3: split-f16 MFMA score matmul + max/argmax ----------------
// R7: PACKED Q rows, grid 832 = qt(13) x n(64).
// R8 (this round): accL split into accL0 (qh*kl) + accL1 (ql*kh) — three
// INDEPENDENT 8-deep MFMA chains interleaved at dependent-distance 3, replacing
// the distance-1 accL chain (16 dependent updates). R7 showed k3 is not
// work-bound (-18.75% work -> -4.5% time); dep-latency is the hypothesis.
// Combine: sv = fmaf(accL0+accL1, 2^-10, accH).
__launch_bounds__(256, 3)
__global__ void k3_score(const _Float16* __restrict__ qg, const _Float16* __restrict__ kg,
                         float* __restrict__ bscore, int* __restrict__ bidx) {
    __shared__ _Float16 Kbuf[2][32 * 256];   // 16 KB each
    const int blk = blockIdx.x;
    const int n = blk & 63, qt = blk >> 6;   // qt in [0,13)
    const int t = threadIdx.x, w = t >> 6, l = t & 63;
    const int lrow = l & 31, khalf = l >> 5;

    // Q fragments: one 32-row group per wave, [c=8][hi/lo]
    const int grp = qt * 4 + w;              // group in [0,52); >=49 are ghosts
    half8 qf[8][2];
    #pragma unroll
    for (int c = 0; c < 8; c++)
        #pragma unroll
        for (int h = 0; h < 2; h++)
            qf[c][h] = ((const half8*)qg)[(size_t)(grp * 16 + c * 2 + h) * 64 + l];

    const _Float16* ksrc = kg + (size_t)n * KPAD * 256;

    float best[16];
    int bestkt[16];
    #pragma unroll
    for (int g = 0; g < 16; g++) { best[g] = -INFINITY; bestkt[g] = 0; }

    // stage chunk 0 (16 KB): wave-uniform base + lane*16
    #pragma unroll
    for (int rd = 0; rd < 4; rd++) {
        int e = (rd * 4 + w) * 512 + l * 8;
        GLOAD_LDS16(ksrc + e, &Kbuf[0][0] + e);
    }

    for (int kt = 0; kt < 14; kt++) {
        __syncthreads();                       // drains vmcnt -> chunk kt ready
        if (kt < 13) {
            const _Float16* src = ksrc + (size_t)(kt + 1) * (32 * 256);
            _Float16* dst = &Kbuf[(kt + 1) & 1][0];
            #pragma unroll
            for (int rd = 0; rd < 4; rd++) {
                int e = (rd * 4 + w) * 512 + l * 8;
                GLOAD_LDS16(src + e, dst + e);
            }
        }
        const _Float16* krow = &Kbuf[kt & 1][0] + lrow * 256;
        f32x16 accH = zero16(), accL0 = zero16(), accL1 = zero16();
        // software-pipelined B-frag reads: c+1 issued before c's MFMAs
        half8 bh = *(const half8*)(krow + ((khalf ^ lrow) * 8));
        half8 bl = *(const half8*)(krow + (((16 + khalf) ^ lrow) * 8));
        #pragma unroll
        for (int c = 0; c < 8; c++) {
            half8 nbh, nbl;
            if (c < 7) {
                nbh = *(const half8*)(krow + ((((c + 1) * 2 + khalf) ^ lrow) * 8));
                nbl = *(const half8*)(krow + (((16 + (c + 1) * 2 + khalf) ^ lrow) * 8));
            }
            // three independent chains, dependent-distance 3
            accH  = mfma_f16(qf[c][0], bh, accH);
            accL0 = mfma_f16(qf[c][0], bl, accL0);
            accL1 = mfma_f16(qf[c][1], bh, accL1);
            bh = nbh; bl = nbl;
        }
        const int kp = kt * 32 + lrow;
        const bool valid = kp < KN;
        #pragma unroll
        for (int g = 0; g < 16; g++) {
            float sv = fmaf(accL0[g] + accL1[g], 0.0009765625f, accH[g]);
            // strict > with ascending kp => numpy first-index tie-break per lane
            if (valid && (sv > best[g])) { best[g] = sv; bestkt[g] = kt; }
        }
    }

    // cross-lane argmax reduce within each 32-lane half
    #pragma unroll
    for (int g = 0; g < 16; g++) {
        float sv = best[g];
        int kp = bestkt[g] * 32 + lrow;
        for (int msk = 1; msk < 32; msk <<= 1) {
            float os = __shfl_xor(sv, msk, 64);
            int okp = __shfl_xor(kp, msk, 64);
            if (os > sv || (os == sv && okp < kp)) { sv = os; kp = okp; }
        }
        if (lrow == 0) {
            int row = (g & 3) + 8 * (g >> 2) + 4 * khalf;
            int mq = grp * 32 + row;               // packed row
            if (mq < QROWS) {
                bscore[(size_t)mq * 64 + n] = sv;
                bidx[(size_t)mq * 64 + n] = kp;
            }
        }
    }
}

// ---------------- K4: softmax + gather-weight V + projection + fused mc conv ----------------
// R7: one block per packed row j (grid 1544 x 256), 4 waves split the 64-n
// gather 16 each (rs/idx via intra-wave shuffles), tree-sum in LDS, wave 0
// does projection + mc conv.
__global__ void k4_out(const float* __restrict__ query,
                       const float* __restrict__ qfeat, const float* __restrict__ vfeat,
                       const float* __restrict__ bscore, const int* __restrict__ bidx,
                       const float* __restrict__ q_scale,
                       const float* __restrict__ mw, const float* __restrict__ mb,
                       const float* __restrict__ mkey,
                       const float* __restrict__ ow, const float* __restrict__ ob,
                       float* __restrict__ out) {
    __shared__ float pS[4][128];
    const int t = threadIdx.x, wv = t >> 6, l = t & 63;
    const int j = blockIdx.x;                // 0..1543 packed row
    const int m = j / QN, qpos = j - m * QN;
    const int mq = m * QPAD + qpos;          // qfeat/q_scale layout

    float s = bscore[(size_t)j * 64 + l];
    int idx = bidx[(size_t)j * 64 + l];
    float msv = qfeat[(size_t)mq * 128 + l] * mkey[l]
              + qfeat[(size_t)mq * 128 + 64 + l] * mkey[64 + l];
    #pragma unroll
    for (int msk = 1; msk < 64; msk <<= 1) msv += __shfl_xor(msv, msk, 64);
    float mx = s;
    #pragma unroll
    for (int msk = 1; msk < 64; msk <<= 1) mx = fmaxf(mx, __shfl_xor(mx, msk, 64));
    mx = fmaxf(mx, msv);
    float e = expf(s - mx);
    float sum = e;
    #pragma unroll
    for (int msk = 1; msk < 64; msk <<= 1) sum += __shfl_xor(sum, msk, 64);
    float ems = expf(msv - mx);
    float inv = 1.f / (sum + ems);
    float rs = e * inv, msw = ems * inv;

    // wave wv gathers nn in [16*wv, 16*wv+16)
    float ax = 0.f, ay = 0.f;
    #pragma unroll
    for (int k = 0; k < 16; k++) {
        int nn = wv * 16 + k;
        float r = __shfl(rs, nn, 64);
        int  id = __shfl(idx, nn, 64);
        const float2 v = *(const float2*)&vfeat[((size_t)nn * KPAD + id) * 128 + 2 * l];
        ax = fmaf(r, v.x, ax);
        ay = fmaf(r, v.y, ay);
    }
    pS[wv][2 * l] = ax; pS[wv][2 * l + 1] = ay;
    __syncthreads();
    if (t < 128) pS[0][t] = (pS[0][t] + pS[1][t]) + (pS[2][t] + pS[3][t]);
    __syncthreads();
    if (wv == 0 && l < 32) {
        float p = 0.f;
        #pragma unroll
        for (int h4 = 0; h4 < 32; h4++) {
            const float4 wv4 = *(const float4*)&pS[0][h4 * 4];
            const float4 o4 = *(const float4*)&ow[l * 128 + h4 * 4];
            p += wv4.x * o4.x + wv4.y * o4.y + wv4.z * o4.z + wv4.w * o4.w;
        }
        p += (1.f - msw) * ob[l];
        // fused mc conv: mc[m, 32+qpos+l] = mb + sum_j mw[j]*query[m, tpos+j-63]
        float mcv = mb[0];
        const int tpos = 32 + qpos + l;
        for (int jj = 0; jj < 64; jj++) {
            int qi = tpos + jj - 63;
            if (qi >= 0) mcv = fmaf(mw[jj], query[m * 256 + qi], mcv);
        }
        float outv = q_scale[mq] * p + msw * mcv;
        out[(size_t)j * 32 + l] = outv;
    }
}

extern "C" void kernel_launch(void* const* d_in, const int* in_sizes, int n_in,
                              void* d_out, int out_size, void* d_ws, size_t ws_size,
                              hipStream_t stream) {
    const float* query = (const float*)d_in[0];
    const float* ref   = (const float*)d_in[1];
    const float* qw    = (const float*)d_in[2];
    const float* qb    = (const float*)d_in[3];
    const float* kw    = (const float*)d_in[4];
    const float* kb    = (const float*)d_in[5];
    const float* vw    = (const float*)d_in[6];
    const float* vb    = (const float*)d_in[7];
    const float* mw    = (const float*)d_in[8];
    const float* mb    = (const float*)d_in[9];
    const float* ow    = (const float*)d_in[10];
    const float* ob    = (const float*)d_in[11];
    const float* mkey  = (const float*)d_in[12];
    float* out = (float*)d_out;

    // workspace layout (floats), 16B-aligned; total 8128512 fl = 32.5 MB
    float* ws = (float*)d_ws;
    float* q_scale = ws;                          // 2048
    float* qfeat   = ws + 2048;                   // 262144 -> 264192
    float* bscore  = ws + 264192;                 // 131072 (uses 98816) -> 395264
    int*   bidx    = (int*)(ws + 395264);         // 131072 (uses 98816) -> 526336
    _Float16* qg   = (_Float16*)(ws + 526336);    // 524288 halfs -> 788480
    _Float16* kg   = (_Float16*)(ws + 788480);    // 7340032 halfs -> 4458496
    float* vfeat   = ws + 4458496;                // 3670016 -> 8128512

    hipLaunchKernelGGL(kA_feat, dim3(480), dim3(256), 0, stream,
                       query, ref, qw, qb, kw, kb, vw, vb,
                       q_scale, qfeat, qg, kg, vfeat);
    hipLaunchKernelGGL(k3_score, dim3(832), dim3(256), 0, stream,
                       qg, kg, bscore, bidx);
    hipLaunchKernelGGL(k4_out, dim3(1544), dim3(256), 0, stream,
                       query, qfeat, vfeat, bscore, bidx, q_scale, mw, mb, mkey, ow, ob, out);
}

// Round 9
// 199.930 us; speedup vs baseline: 1.0376x; 1.0376x over previous
//
#include <hip/hip_runtime.h>
#include <cmath>

// Problem constants
#define M_B   8
#define LQ    256
#define N_B   64
#define LR    512
#define COND  64
#define PRED  32
#define DH    128
#define QN    193      // LQ-COND+1
#define KN    417      // (LR-PRED)-COND+1
#define QPAD  256      // per-m padded q rows (qfeat/q_scale layout only)
#define KPAD  448      // padded kpos (14 chunks of 32)
#define QROWS 1544     // M_B*QN packed q rows (R7)
#define QGRPS 49       // ceil(QROWS/32)

typedef _Float16 half8 __attribute__((ext_vector_type(8)));
typedef float f32x16 __attribute__((ext_vector_type(16)));

__device__ __forceinline__ f32x16 mfma_f16(half8 a, half8 b, f32x16 c) {
    return __builtin_amdgcn_mfma_f32_32x32x16_f16(a, b, c, 0, 0, 0);
}
__device__ __forceinline__ f32x16 zero16() {
    f32x16 z;
    #pragma unroll
    for (int i = 0; i < 16; i++) z[i] = 0.f;
    return z;
}

#define GLOAD_LDS16(g, l) __builtin_amdgcn_global_load_lds( \
    (const __attribute__((address_space(1))) void*)(g), \
    (__attribute__((address_space(3))) void*)(l), 16, 0, 0)

// Force a float to live in a VGPR (blocks LDS-rematerialization of loads).
#define PIN_V(x) asm volatile("" : "+v"(x))

// ---------------- KA: fused feature kernel ----------------
// R6: scan-free (relative window sums, translation-invariant).
// R7: qg emitted in PACKED row layout (prow = m*QN + qpos, 49 groups of 32).
// R8: ghost-frag memset dropped (worth ~15 us of fixed dispatch overhead);
// ghost A-rows only pollute ghost C-rows (row-independence), ghost best-slots
// are write-guarded, all reads in-bounds. Empirically validated in R8.
__launch_bounds__(256, 2)
__global__ void kA_feat(const float* __restrict__ query, const float* __restrict__ ref,
                        const float* __restrict__ qw, const float* __restrict__ qb,
                        const float* __restrict__ kw, const float* __restrict__ kb,
                        const float* __restrict__ vw, const float* __restrict__ vb,
                        float* __restrict__ q_scale, float* __restrict__ qfeat,
                        _Float16* __restrict__ qg,
                        _Float16* __restrict__ kg, float* __restrict__ vfeat) {
    __shared__ float x[512];
    __shared__ float buf[128 * 65];
    const int t = threadIdx.x;
    const int kl = t & 63;
    const int hq = __builtin_amdgcn_readfirstlane(t >> 6);

    if (blockIdx.x < 448) {
        // ================= K/V branch =================
        const int n = blockIdx.x / 7, chunk = blockIdx.x % 7;
        x[t] = ref[n * 512 + t];
        x[t + 256] = ref[n * 512 + t + 256];
        __syncthreads();

        const int kp = chunk * 64 + kl;
        const bool vkp = kp < KN;
        // relative window sums: csw[j] = sum ref[kp+1 .. kp+j]  (csw[0] = 0)
        float csw[64];
        float run = 0.f, mn = 0.f, mx = 0.f;
        csw[0] = 0.f;
        #pragma unroll
        for (int j = 1; j < 64; j++) {
            run += x[kp + j];                // kp+63 <= 510, in range
            csw[j] = run;
            mn = fminf(mn, run);
            mx = fmaxf(mx, run);
        }
        float scv = mx - mn; if (scv == 0.f) scv = 1.f;
        const float inv = 1.f / scv;
        #pragma unroll
        for (int j = 0; j < 64; j++) { csw[j] -= mn; PIN_V(csw[j]); }

        // ---- k features ----
        for (int hh = 0; hh < 32; hh++) {
            const int h = hq * 32 + hh;      // wave-uniform -> s_load weights
            const float* wrow = kw + h * 64;
            float a0 = 0.f, a1 = 0.f, a2 = 0.f, a3 = 0.f;
            #pragma unroll
            for (int j = 0; j < 64; j += 4) {
                a0 = fmaf(wrow[j],     csw[j],     a0);
                a1 = fmaf(wrow[j + 1], csw[j + 1], a1);
                a2 = fmaf(wrow[j + 2], csw[j + 2], a2);
                a3 = fmaf(wrow[j + 3], csw[j + 3], a3);
            }
            float kraw = (a0 + a1) + (a2 + a3);
            float kval = vkp ? kraw * inv + kb[h] : 0.f;
            buf[h * 65 + (kl ^ (h >> 3))] = kval;
        }
        __syncthreads();
        // emit kg: 64 kp x 32 granules (16 hi + 16 lo), swizzled by kp&31
        {
            const size_t nb = ((size_t)n * KPAD + chunk * 64) * 256;
            #pragma unroll
            for (int r = 0; r < 8; r++) {
                int task = r * 256 + t;
                int kp_l = task >> 5, g = task & 31;
                int cb = g & 15, lo = g >> 4;
                half8 hv;
                #pragma unroll
                for (int jj = 0; jj < 8; jj++) {
                    float v = buf[(cb * 8 + jj) * 65 + (kp_l ^ cb)];
                    _Float16 hi = (_Float16)v;
                    hv[jj] = lo ? (_Float16)((v - (float)hi) * 1024.0f) : hi;
                }
                *(half8*)&kg[nb + (size_t)kp_l * 256 + ((size_t)(g ^ (kp_l & 31)) << 3)] = hv;
            }
        }
        __syncthreads();
        // ---- v features ----
        float refw[32];
        #pragma unroll
        for (int j = 0; j < 32; j++) {
            int ri = 64 + kp + j;
            refw[j] = (ri < 512) ? x[ri] : 0.f;
            PIN_V(refw[j]);
        }
        for (int hh = 0; hh < 32; hh++) {
            const int h = hq * 32 + hh;
            const float* vrow = vw + h * 32;
            float b0 = 0.f, b1 = 0.f;
            #pragma unroll
            for (int j = 0; j < 32; j += 2) {
                b0 = fmaf(vrow[j],     refw[j],     b0);
                b1 = fmaf(vrow[j + 1], refw[j + 1], b1);
            }
            float vval = vkp ? (b0 + b1) * inv + vb[h] : 0.f;
            buf[h * 65 + (kl ^ (h >> 3))] = vval;
        }
        __syncthreads();
        {
            const size_t vb0 = ((size_t)n * KPAD + chunk * 64) * 128;
            #pragma unroll
            for (int r = 0; r < 8; r++) {
                int idx = r * 256 + t;
                int kp_l = idx >> 5, c4 = idx & 31;
                float4 o;
                o.x = buf[(c4 * 4 + 0) * 65 + (kp_l ^ ((c4 * 4 + 0) >> 3))];
                o.y = buf[(c4 * 4 + 1) * 65 + (kp_l ^ ((c4 * 4 + 1) >> 3))];
                o.z = buf[(c4 * 4 + 2) * 65 + (kp_l ^ ((c4 * 4 + 2) >> 3))];
                o.w = buf[(c4 * 4 + 3) * 65 + (kp_l ^ ((c4 * 4 + 3) >> 3))];
                *(float4*)&vfeat[vb0 + (size_t)kp_l * 128 + c4 * 4] = o;
            }
        }
    } else {
        // ================= Q branch =================
        const int id = blockIdx.x - 448;
        const int m = id >> 2, qc = id & 3;
        x[t] = query[m * 256 + t];
        __syncthreads();

        const int qpos = qc * 64 + kl;
        const bool vq = qpos < QN;
        const int base = vq ? qpos : (QN - 1);
        float csw[64];
        float run = 0.f, mn = 0.f, mx = 0.f;
        csw[0] = 0.f;
        #pragma unroll
        for (int j = 1; j < 64; j++) {
            run += x[base + j];              // base+63 <= 255, in range
            csw[j] = run;
            mn = fminf(mn, run);
            mx = fmaxf(mx, run);
        }
        float sc = mx - mn; if (sc == 0.f) sc = 1.f;
        const float inv = 1.f / sc;
        if (t < 64) q_scale[m * QPAD + qpos] = vq ? sc : 1.f;
        #pragma unroll
        for (int j = 0; j < 64; j++) { csw[j] -= mn; PIN_V(csw[j]); }

        for (int hh = 0; hh < 32; hh++) {
            const int h = hq * 32 + hh;      // wave-uniform -> s_load weights
            const float* wrow = qw + h * 64;
            float a0 = 0.f, a1 = 0.f, a2 = 0.f, a3 = 0.f;
            #pragma unroll
            for (int j = 0; j < 64; j += 4) {
                a0 = fmaf(wrow[j],     csw[j],     a0);
                a1 = fmaf(wrow[j + 1], csw[j + 1], a1);
                a2 = fmaf(wrow[j + 2], csw[j + 2], a2);
                a3 = fmaf(wrow[j + 3], csw[j + 3], a3);
            }
            float raw = (a0 + a1) + (a2 + a3);
            float val = vq ? raw * inv + qb[h] : 0.f;
            buf[h * 65 + (kl ^ (h >> 3))] = val;
        }
        __syncthreads();
        // emit qfeat (coalesced float4, QPAD layout — unchanged)
        const size_t qb0 = ((size_t)m * QPAD + qc * 64) * 128;
        #pragma unroll
        for (int r = 0; r < 8; r++) {
            int idx = r * 256 + t;
            int qp_l = idx >> 5, c4 = idx & 31;
            float4 o;
            o.x = buf[(c4 * 4 + 0) * 65 + (qp_l ^ ((c4 * 4 + 0) >> 3))];
            o.y = buf[(c4 * 4 + 1) * 65 + (qp_l ^ ((c4 * 4 + 1) >> 3))];
            o.z = buf[(c4 * 4 + 2) * 65 + (qp_l ^ ((c4 * 4 + 2) >> 3))];
            o.w = buf[(c4 * 4 + 3) * 65 + (qp_l ^ ((c4 * 4 + 3) >> 3))];
            *(float4*)&qfeat[qb0 + (size_t)qp_l * 128 + c4 * 4] = o;
        }
        // emit qg frag-major hi/lo, PACKED rows: prow = m*QN + qpos
        #pragma unroll
        for (int r = 0; r < 8; r++) {
            int idx = r * 256 + t;
            int qp_l = idx >> 5, g = idx & 31;
            int c = g >> 2, kh = (g >> 1) & 1, lo = g & 1;
            int qp2 = qc * 64 + qp_l;
            if (qp2 < QN) {
                half8 hv;
                #pragma unroll
                for (int jj = 0; jj < 8; jj++) {
                    int h = c * 16 + kh * 8 + jj;
                    float v = buf[h * 65 + (qp_l ^ (h >> 3))];
                    _Float16 hi = (_Float16)v;
                    hv[jj] = lo ? (_Float16)((v - (float)hi) * 1024.0f) : hi;
                }
                int prow = m * QN + qp2;
                int grp = prow >> 5;
                size_t fb = (size_t)(grp * 16 + c * 2 + lo);
                *(half8*)&qg[fb * 512 + (size_t)(kh * 32 + (prow & 31)) * 8] = hv;
            }
        }
    }
}

// ---------------- K3: split-f16 MFMA score matmul + max/argmax ----------------
// R7 version restored (55.8 us known-good): two accumulators accH/accL.
// R8 post-mortem: a third f32x16 acc chain spilled to scratch at the (256,3)
// cap (WRITE 6.2->9.3 MB, MfmaUtil 26->18, k3 79 us). Dep-chain splitting is
// rejected at this register budget. k3 exploration closed: work-reduction
// weak (R7), occupancy null (R3/R4), staging removal negative (R5), dep
// chains negative-via-spill (R8).
__launch_bounds__(256, 3)
__global__ void k3_score(const _Float16* __restrict__ qg, const _Float16* __restrict__ kg,
                         float* __restrict__ bscore, int* __restrict__ bidx) {
    __shared__ _Float16 Kbuf[2][32 * 256];   // 16 KB each
    const int blk = blockIdx.x;
    const int n = blk & 63, qt = blk >> 6;   // qt in [0,13)
    const int t = threadIdx.x, w = t >> 6, l = t & 63;
    const int lrow = l & 31, khalf = l >> 5;

    // Q fragments: one 32-row group per wave, [c=8][hi/lo]
    const int grp = qt * 4 + w;              // group in [0,52); >=49 are ghosts
    half8 qf[8][2];
    #pragma unroll
    for (int c = 0; c < 8; c++)
        #pragma unroll
        for (int h = 0; h < 2; h++)
            qf[c][h] = ((const half8*)qg)[(size_t)(grp * 16 + c * 2 + h) * 64 + l];

    const _Float16* ksrc = kg + (size_t)n * KPAD * 256;

    float best[16];
    int bestkt[16];
    #pragma unroll
    for (int g = 0; g < 16; g++) { best[g] = -INFINITY; bestkt[g] = 0; }

    // stage chunk 0 (16 KB): wave-uniform base + lane*16
    #pragma unroll
    for (int rd = 0; rd < 4; rd++) {
        int e = (rd * 4 + w) * 512 + l * 8;
        GLOAD_LDS16(ksrc + e, &Kbuf[0][0] + e);
    }

    for (int kt = 0; kt < 14; kt++) {
        __syncthreads();                       // drains vmcnt -> chunk kt ready
        if (kt < 13) {
            const _Float16* src = ksrc + (size_t)(kt + 1) * (32 * 256);
            _Float16* dst = &Kbuf[(kt + 1) & 1][0];
            #pragma unroll
            for (int rd = 0; rd < 4; rd++) {
                int e = (rd * 4 + w) * 512 + l * 8;
                GLOAD_LDS16(src + e, dst + e);
            }
        }
        const _Float16* krow = &Kbuf[kt & 1][0] + lrow * 256;
        f32x16 accH = zero16(), accL = zero16();
        // software-pipelined B-frag reads: c+1 issued before c's MFMAs
        half8 bh = *(const half8*)(krow + ((khalf ^ lrow) * 8));
        half8 bl = *(const half8*)(krow + (((16 + khalf) ^ lrow) * 8));
        #pragma unroll
        for (int c = 0; c < 8; c++) {
            half8 nbh, nbl;
            if (c < 7) {
                nbh = *(const half8*)(krow + ((((c + 1) * 2 + khalf) ^ lrow) * 8));
                nbl = *(const half8*)(krow + (((16 + (c + 1) * 2 + khalf) ^ lrow) * 8));
            }
            accH = mfma_f16(qf[c][0], bh, accH);
            accL = mfma_f16(qf[c][0], bl, accL);
            accL = mfma_f16(qf[c][1], bh, accL);
            bh = nbh; bl = nbl;
        }
        const int kp = kt * 32 + lrow;
        const bool valid = kp < KN;
        #pragma unroll
        for (int g = 0; g < 16; g++) {
            float sv = fmaf(accL[g], 0.0009765625f, accH[g]);
            // strict > with ascending kp => numpy first-index tie-break per lane
            if (valid && (sv > best[g])) { best[g] = sv; bestkt[g] = kt; }
        }
    }

    // cross-lane argmax reduce within each 32-lane half
    #pragma unroll
    for (int g = 0; g < 16; g++) {
        float sv = best[g];
        int kp = bestkt[g] * 32 + lrow;
        for (int msk = 1; msk < 32; msk <<= 1) {
            float os = __shfl_xor(sv, msk, 64);
            int okp = __shfl_xor(kp, msk, 64);
            if (os > sv || (os == sv && okp < kp)) { sv = os; kp = okp; }
        }
        if (lrow == 0) {
            int row = (g & 3) + 8 * (g >> 2) + 4 * khalf;
            int mq = grp * 32 + row;               // packed row
            if (mq < QROWS) {
                bscore[(size_t)mq * 64 + n] = sv;
                bidx[(size_t)mq * 64 + n] = kp;
            }
        }
    }
}

// ---------------- K4: softmax + gather-weight V + projection + fused mc conv ----------------
// R7: one block per packed row j (grid 1544 x 256), 4 waves split the 64-n
// gather 16 each (rs/idx via intra-wave shuffles), tree-sum in LDS, wave 0
// does projection + mc conv.
__global__ void k4_out(const float* __restrict__ query,
                       const float* __restrict__ qfeat, const float* __restrict__ vfeat,
                       const float* __restrict__ bscore, const int* __restrict__ bidx,
                       const float* __restrict__ q_scale,
                       const float* __restrict__ mw, const float* __restrict__ mb,
                       const float* __restrict__ mkey,
                       const float* __restrict__ ow, const float* __restrict__ ob,
                       float* __restrict__ out) {
    __shared__ float pS[4][128];
    const int t = threadIdx.x, wv = t >> 6, l = t & 63;
    const int j = blockIdx.x;                // 0..1543 packed row
    const int m = j / QN, qpos = j - m * QN;
    const int mq = m * QPAD + qpos;          // qfeat/q_scale layout

    float s = bscore[(size_t)j * 64 + l];
    int idx = bidx[(size_t)j * 64 + l];
    float msv = qfeat[(size_t)mq * 128 + l] * mkey[l]
              + qfeat[(size_t)mq * 128 + 64 + l] * mkey[64 + l];
    #pragma unroll
    for (int msk = 1; msk < 64; msk <<= 1) msv += __shfl_xor(msv, msk, 64);
    float mx = s;
    #pragma unroll
    for (int msk = 1; msk < 64; msk <<= 1) mx = fmaxf(mx, __shfl_xor(mx, msk, 64));
    mx = fmaxf(mx, msv);
    float e = expf(s - mx);
    float sum = e;
    #pragma unroll
    for (int msk = 1; msk < 64; msk <<= 1) sum += __shfl_xor(sum, msk, 64);
    float ems = expf(msv - mx);
    float inv = 1.f / (sum + ems);
    float rs = e * inv, msw = ems * inv;

    // wave wv gathers nn in [16*wv, 16*wv+16)
    float ax = 0.f, ay = 0.f;
    #pragma unroll
    for (int k = 0; k < 16; k++) {
        int nn = wv * 16 + k;
        float r = __shfl(rs, nn, 64);
        int  id = __shfl(idx, nn, 64);
        const float2 v = *(const float2*)&vfeat[((size_t)nn * KPAD + id) * 128 + 2 * l];
        ax = fmaf(r, v.x, ax);
        ay = fmaf(r, v.y, ay);
    }
    pS[wv][2 * l] = ax; pS[wv][2 * l + 1] = ay;
    __syncthreads();
    if (t < 128) pS[0][t] = (pS[0][t] + pS[1][t]) + (pS[2][t] + pS[3][t]);
    __syncthreads();
    if (wv == 0 && l < 32) {
        float p = 0.f;
        #pragma unroll
        for (int h4 = 0; h4 < 32; h4++) {
            const float4 wv4 = *(const float4*)&pS[0][h4 * 4];
            const float4 o4 = *(const float4*)&ow[l * 128 + h4 * 4];
            p += wv4.x * o4.x + wv4.y * o4.y + wv4.z * o4.z + wv4.w * o4.w;
        }
        p += (1.f - msw) * ob[l];
        // fused mc conv: mc[m, 32+qpos+l] = mb + sum_j mw[j]*query[m, tpos+j-63]
        float mcv = mb[0];
        const int tpos = 32 + qpos + l;
        for (int jj = 0; jj < 64; jj++) {
            int qi = tpos + jj - 63;
            if (qi >= 0) mcv = fmaf(mw[jj], query[m * 256 + qi], mcv);
        }
        float outv = q_scale[mq] * p + msw * mcv;
        out[(size_t)j * 32 + l] = outv;
    }
}

extern "C" void kernel_launch(void* const* d_in, const int* in_sizes, int n_in,
                              void* d_out, int out_size, void* d_ws, size_t ws_size,
                              hipStream_t stream) {
    const float* query = (const float*)d_in[0];
    const float* ref   = (const float*)d_in[1];
    const float* qw    = (const float*)d_in[2];
    const float* qb    = (const float*)d_in[3];
    const float* kw    = (const float*)d_in[4];
    const float* kb    = (const float*)d_in[5];
    const float* vw    = (const float*)d_in[6];
    const float* vb    = (const float*)d_in[7];
    const float* mw    = (const float*)d_in[8];
    const float* mb    = (const float*)d_in[9];
    const float* ow    = (const float*)d_in[10];
    const float* ob    = (const float*)d_in[11];
    const float* mkey  = (const float*)d_in[12];
    float* out = (float*)d_out;

    // workspace layout (floats), 16B-aligned; total 8128512 fl = 32.5 MB
    float* ws = (float*)d_ws;
    float* q_scale = ws;                          // 2048
    float* qfeat   = ws + 2048;                   // 262144 -> 264192
    float* bscore  = ws + 264192;                 // 131072 (uses 98816) -> 395264
    int*   bidx    = (int*)(ws + 395264);         // 131072 (uses 98816) -> 526336
    _Float16* qg   = (_Float16*)(ws + 526336);    // 524288 halfs -> 788480
    _Float16* kg   = (_Float16*)(ws + 788480);    // 7340032 halfs -> 4458496
    float* vfeat   = ws + 4458496;                // 3670016 -> 8128512

    hipLaunchKernelGGL(kA_feat, dim3(480), dim3(256), 0, stream,
                       query, ref, qw, qb, kw, kb, vw, vb,
                       q_scale, qfeat, qg, kg, vfeat);
    hipLaunchKernelGGL(k3_score, dim3(832), dim3(256), 0, stream,
                       qg, kg, bscore, bidx);
    hipLaunchKernelGGL(k4_out, dim3(1544), dim3(256), 0, stream,
                       query, qfeat, vfeat, bscore, bidx, q_scale, mw, mb, mkey, ow, ob, out);
}

// Round 11
// 199.079 us; speedup vs baseline: 1.0420x; 1.0043x over previous
//
#include <hip/hip_runtime.h>
#include <cmath>

// Problem constants
#define M_B   8
#define LQ    256
#define N_B   64
#define LR    512
#define COND  64
#define PRED  32
#define DH    128
#define QN    193      // LQ-COND+1
#define KN    417      // (LR-PRED)-COND+1
#define QPAD  256      // per-m padded q rows (qfeat/q_scale layout only)
#define KPAD  448      // padded kpos (14 chunks of 32)
#define QROWS 1544     // M_B*QN packed q rows (R7)
#define QGRPS 49       // ceil(QROWS/32)

typedef _Float16 half8 __attribute__((ext_vector_type(8)));
typedef float f32x16 __attribute__((ext_vector_type(16)));

__device__ __forceinline__ f32x16 mfma_f16(half8 a, half8 b, f32x16 c) {
    return __builtin_amdgcn_mfma_f32_32x32x16_f16(a, b, c, 0, 0, 0);
}
__device__ __forceinline__ f32x16 zero16() {
    f32x16 z;
    #pragma unroll
    for (int i = 0; i < 16; i++) z[i] = 0.f;
    return z;
}

#define GLOAD_LDS16(g, l) __builtin_amdgcn_global_load_lds( \
    (const __attribute__((address_space(1))) void*)(g), \
    (__attribute__((address_space(3))) void*)(l), 16, 0, 0)

// Force a float to live in a VGPR (blocks LDS-rematerialization of loads).
#define PIN_V(x) asm volatile("" : "+v"(x))

// ---------------- KA: fused feature kernel ----------------
// R6: scan-free (relative window sums, translation-invariant).
// R7: qg emitted in PACKED row layout (prow = m*QN + qpos, 49 groups of 32).
// R8/R9: no ghost memset (ghost rows provably inert; R8/R9 passed).
__launch_bounds__(256, 2)
__global__ void kA_feat(const float* __restrict__ query, const float* __restrict__ ref,
                        const float* __restrict__ qw, const float* __restrict__ qb,
                        const float* __restrict__ kw, const float* __restrict__ kb,
                        const float* __restrict__ vw, const float* __restrict__ vb,
                        float* __restrict__ q_scale, float* __restrict__ qfeat,
                        _Float16* __restrict__ qg,
                        _Float16* __restrict__ kg, float* __restrict__ vfeat) {
    __shared__ float x[512];
    __shared__ float buf[128 * 65];
    const int t = threadIdx.x;
    const int kl = t & 63;
    const int hq = __builtin_amdgcn_readfirstlane(t >> 6);

    if (blockIdx.x < 448) {
        // ================= K/V branch =================
        const int n = blockIdx.x / 7, chunk = blockIdx.x % 7;
        x[t] = ref[n * 512 + t];
        x[t + 256] = ref[n * 512 + t + 256];
        __syncthreads();

        const int kp = chunk * 64 + kl;
        const bool vkp = kp < KN;
        // relative window sums: csw[j] = sum ref[kp+1 .. kp+j]  (csw[0] = 0)
        float csw[64];
        float run = 0.f, mn = 0.f, mx = 0.f;
        csw[0] = 0.f;
        #pragma unroll
        for (int j = 1; j < 64; j++) {
            run += x[kp + j];                // kp+63 <= 510, in range
            csw[j] = run;
            mn = fminf(mn, run);
            mx = fmaxf(mx, run);
        }
        float scv = mx - mn; if (scv == 0.f) scv = 1.f;
        const float inv = 1.f / scv;
        #pragma unroll
        for (int j = 0; j < 64; j++) { csw[j] -= mn; PIN_V(csw[j]); }

        // ---- k features ----
        for (int hh = 0; hh < 32; hh++) {
            const int h = hq * 32 + hh;      // wave-uniform -> s_load weights
            const float* wrow = kw + h * 64;
            float a0 = 0.f, a1 = 0.f, a2 = 0.f, a3 = 0.f;
            #pragma unroll
            for (int j = 0; j < 64; j += 4) {
                a0 = fmaf(wrow[j],     csw[j],     a0);
                a1 = fmaf(wrow[j + 1], csw[j + 1], a1);
                a2 = fmaf(wrow[j + 2], csw[j + 2], a2);
                a3 = fmaf(wrow[j + 3], csw[j + 3], a3);
            }
            float kraw = (a0 + a1) + (a2 + a3);
            float kval = vkp ? kraw * inv + kb[h] : 0.f;
            buf[h * 65 + (kl ^ (h >> 3))] = kval;
        }
        __syncthreads();
        // emit kg: 64 kp x 32 granules (16 hi + 16 lo), swizzled by kp&31
        {
            const size_t nb = ((size_t)n * KPAD + chunk * 64) * 256;
            #pragma unroll
            for (int r = 0; r < 8; r++) {
                int task = r * 256 + t;
                int kp_l = task >> 5, g = task & 31;
                int cb = g & 15, lo = g >> 4;
                half8 hv;
                #pragma unroll
                for (int jj = 0; jj < 8; jj++) {
                    float v = buf[(cb * 8 + jj) * 65 + (kp_l ^ cb)];
                    _Float16 hi = (_Float16)v;
                    hv[jj] = lo ? (_Float16)((v - (float)hi) * 1024.0f) : hi;
                }
                *(half8*)&kg[nb + (size_t)kp_l * 256 + ((size_t)(g ^ (kp_l & 31)) << 3)] = hv;
            }
        }
        __syncthreads();
        // ---- v features ----
        float refw[32];
        #pragma unroll
        for (int j = 0; j < 32; j++) {
            int ri = 64 + kp + j;
            refw[j] = (ri < 512) ? x[ri] : 0.f;
            PIN_V(refw[j]);
        }
        for (int hh = 0; hh < 32; hh++) {
            const int h = hq * 32 + hh;
            const float* vrow = vw + h * 32;
            float b0 = 0.f, b1 = 0.f;
            #pragma unroll
            for (int j = 0; j < 32; j += 2) {
                b0 = fmaf(vrow[j],     refw[j],     b0);
                b1 = fmaf(vrow[j + 1], refw[j + 1], b1);
            }
            float vval = vkp ? (b0 + b1) * inv + vb[h] : 0.f;
            buf[h * 65 + (kl ^ (h >> 3))] = vval;
        }
        __syncthreads();
        {
            const size_t vb0 = ((size_t)n * KPAD + chunk * 64) * 128;
            #pragma unroll
            for (int r = 0; r < 8; r++) {
                int idx = r * 256 + t;
                int kp_l = idx >> 5, c4 = idx & 31;
                float4 o;
                o.x = buf[(c4 * 4 + 0) * 65 + (kp_l ^ ((c4 * 4 + 0) >> 3))];
                o.y = buf[(c4 * 4 + 1) * 65 + (kp_l ^ ((c4 * 4 + 1) >> 3))];
                o.z = buf[(c4 * 4 + 2) * 65 + (kp_l ^ ((c4 * 4 + 2) >> 3))];
                o.w = buf[(c4 * 4 + 3) * 65 + (kp_l ^ ((c4 * 4 + 3) >> 3))];
                *(float4*)&vfeat[vb0 + (size_t)kp_l * 128 + c4 * 4] = o;
            }
        }
    } else {
        // ================= Q branch =================
        const int id = blockIdx.x - 448;
        const int m = id >> 2, qc = id & 3;
        x[t] = query[m * 256 + t];
        __syncthreads();

        const int qpos = qc * 64 + kl;
        const bool vq = qpos < QN;
        const int base = vq ? qpos : (QN - 1);
        float csw[64];
        float run = 0.f, mn = 0.f, mx = 0.f;
        csw[0] = 0.f;
        #pragma unroll
        for (int j = 1; j < 64; j++) {
            run += x[base + j];              // base+63 <= 255, in range
            csw[j] = run;
            mn = fminf(mn, run);
            mx = fmaxf(mx, run);
        }
        float sc = mx - mn; if (sc == 0.f) sc = 1.f;
        const float inv = 1.f / sc;
        if (t < 64) q_scale[m * QPAD + qpos] = vq ? sc : 1.f;
        #pragma unroll
        for (int j = 0; j < 64; j++) { csw[j] -= mn; PIN_V(csw[j]); }

        for (int hh = 0; hh < 32; hh++) {
            const int h = hq * 32 + hh;      // wave-uniform -> s_load weights
            const float* wrow = qw + h * 64;
            float a0 = 0.f, a1 = 0.f, a2 = 0.f, a3 = 0.f;
            #pragma unroll
            for (int j = 0; j < 64; j += 4) {
                a0 = fmaf(wrow[j],     csw[j],     a0);
                a1 = fmaf(wrow[j + 1], csw[j + 1], a1);
                a2 = fmaf(wrow[j + 2], csw[j + 2], a2);
                a3 = fmaf(wrow[j + 3], csw[j + 3], a3);
            }
            float raw = (a0 + a1) + (a2 + a3);
            float val = vq ? raw * inv + qb[h] : 0.f;
            buf[h * 65 + (kl ^ (h >> 3))] = val;
        }
        __syncthreads();
        // emit qfeat (coalesced float4, QPAD layout — unchanged)
        const size_t qb0 = ((size_t)m * QPAD + qc * 64) * 128;
        #pragma unroll
        for (int r = 0; r < 8; r++) {
            int idx = r * 256 + t;
            int qp_l = idx >> 5, c4 = idx & 31;
            float4 o;
            o.x = buf[(c4 * 4 + 0) * 65 + (qp_l ^ ((c4 * 4 + 0) >> 3))];
            o.y = buf[(c4 * 4 + 1) * 65 + (qp_l ^ ((c4 * 4 + 1) >> 3))];
            o.z = buf[(c4 * 4 + 2) * 65 + (qp_l ^ ((c4 * 4 + 2) >> 3))];
            o.w = buf[(c4 * 4 + 3) * 65 + (qp_l ^ ((c4 * 4 + 3) >> 3))];
            *(float4*)&qfeat[qb0 + (size_t)qp_l * 128 + c4 * 4] = o;
        }
        // emit qg frag-major hi/lo, PACKED rows: prow = m*QN + qpos
        #pragma unroll
        for (int r = 0; r < 8; r++) {
            int idx = r * 256 + t;
            int qp_l = idx >> 5, g = idx & 31;
            int c = g >> 2, kh = (g >> 1) & 1, lo = g & 1;
            int qp2 = qc * 64 + qp_l;
            if (qp2 < QN) {
                half8 hv;
                #pragma unroll
                for (int jj = 0; jj < 8; jj++) {
                    int h = c * 16 + kh * 8 + jj;
                    float v = buf[h * 65 + (qp_l ^ (h >> 3))];
                    _Float16 hi = (_Float16)v;
                    hv[jj] = lo ? (_Float16)((v - (float)hi) * 1024.0f) : hi;
                }
                int prow = m * QN + qp2;
                int grp = prow >> 5;
                size_t fb = (size_t)(grp * 16 + c * 2 + lo);
                *(half8*)&qg[fb * 512 + (size_t)(kh * 32 + (prow & 31)) * 8] = hv;
            }
        }
    }
}

// ---------------- K3: split-f16 MFMA score matmul + max/argmax ----------------
// R10: TWO n per block. Block = (qt, npair); grid 416 = 13 x 32.
// LDS 64 KB = 2 dbuf x 2 n x 16 KB; launch_bounds (256,2) => up to 256 VGPR,
// no spill (R8 lesson: the 3-wave cap spilled a 3rd acc chain; at 2 waves the
// file affords 4 acc chains). Wins: Q-frag prologue amortized over 2 n;
// barriers per unit work halved; n0/n1 accL chains are INDEPENDENT =>
// interleaved MFMAs give dep-distance 2 (R8 mechanism without the spill).
// Score arithmetic order per (row,n,kt) unchanged => bitwise-identical output.
__launch_bounds__(256, 2)
__global__ void k3_score(const _Float16* __restrict__ qg, const _Float16* __restrict__ kg,
                         float* __restrict__ bscore, int* __restrict__ bidx) {
    __shared__ _Float16 Kbuf[2][2][32 * 256];   // [dbuf][n] 16 KB each = 64 KB
    const int blk = blockIdx.x;
    const int np = blk & 31, qt = blk >> 5;   // np in [0,32), qt in [0,13)
    const int n0 = np * 2;
    const int t = threadIdx.x, w = t >> 6, l = t & 63;
    const int lrow = l & 31, khalf = l >> 5;

    // Q fragments: one 32-row group per wave, [c=8][hi/lo] — shared by both n
    const int grp = qt * 4 + w;              // group in [0,52); >=49 are ghosts
    half8 qf[8][2];
    #pragma unroll
    for (int c = 0; c < 8; c++)
        #pragma unroll
        for (int h = 0; h < 2; h++)
            qf[c][h] = ((const half8*)qg)[(size_t)(grp * 16 + c * 2 + h) * 64 + l];

    const _Float16* ksrc0 = kg + (size_t)n0 * KPAD * 256;
    const _Float16* ksrc1 = ksrc0 + (size_t)KPAD * 256;

    float best0[16], best1[16];
    unsigned bkt0[2] = {0u, 0u}, bkt1[2] = {0u, 0u};   // nibble-packed kt
    #pragma unroll
    for (int g = 0; g < 16; g++) { best0[g] = -INFINITY; best1[g] = -INFINITY; }

    // stage chunk 0 for both n (16 KB each): wave-uniform base + lane*16
    #pragma unroll
    for (int rd = 0; rd < 4; rd++) {
        int e = (rd * 4 + w) * 512 + l * 8;
        GLOAD_LDS16(ksrc0 + e, &Kbuf[0][0][0] + e);
        GLOAD_LDS16(ksrc1 + e, &Kbuf[0][1][0] + e);
    }

    for (int kt = 0; kt < 14; kt++) {
        __syncthreads();                       // drains vmcnt -> chunk kt ready
        if (kt < 13) {
            const size_t off = (size_t)(kt + 1) * (32 * 256);
            _Float16* dst0 = &Kbuf[(kt + 1) & 1][0][0];
            _Float16* dst1 = &Kbuf[(kt + 1) & 1][1][0];
            #pragma unroll
            for (int rd = 0; rd < 4; rd++) {
                int e = (rd * 4 + w) * 512 + l * 8;
                GLOAD_LDS16(ksrc0 + off + e, dst0 + e);
                GLOAD_LDS16(ksrc1 + off + e, dst1 + e);
            }
        }
        const _Float16* krow0 = &Kbuf[kt & 1][0][0] + lrow * 256;
        const _Float16* krow1 = &Kbuf[kt & 1][1][0] + lrow * 256;
        f32x16 accH0 = zero16(), accL0 = zero16();
        f32x16 accH1 = zero16(), accL1 = zero16();
        // software-pipelined B-frag reads: c+1 issued before c's MFMAs
        half8 bh0 = *(const half8*)(krow0 + ((khalf ^ lrow) * 8));
        half8 bl0 = *(const half8*)(krow0 + (((16 + khalf) ^ lrow) * 8));
        half8 bh1 = *(const half8*)(krow1 + ((khalf ^ lrow) * 8));
        half8 bl1 = *(const half8*)(krow1 + (((16 + khalf) ^ lrow) * 8));
        #pragma unroll
        for (int c = 0; c < 8; c++) {
            half8 nbh0, nbl0, nbh1, nbl1;
            if (c < 7) {
                const int oh = (((c + 1) * 2 + khalf) ^ lrow) * 8;
                const int ol = (((16 + (c + 1) * 2 + khalf)) ^ lrow) * 8;
                nbh0 = *(const half8*)(krow0 + oh);
                nbl0 = *(const half8*)(krow0 + ol);
                nbh1 = *(const half8*)(krow1 + oh);
                nbl1 = *(const half8*)(krow1 + ol);
            }
            // interleave n0/n1: each accL chain sees dep-distance 2
            accH0 = mfma_f16(qf[c][0], bh0, accH0);
            accH1 = mfma_f16(qf[c][0], bh1, accH1);
            accL0 = mfma_f16(qf[c][0], bl0, accL0);
            accL1 = mfma_f16(qf[c][0], bl1, accL1);
            accL0 = mfma_f16(qf[c][1], bh0, accL0);
            accL1 = mfma_f16(qf[c][1], bh1, accL1);
            bh0 = nbh0; bl0 = nbl0; bh1 = nbh1; bl1 = nbl1;
        }
        const int kp = kt * 32 + lrow;
        const bool valid = kp < KN;
        #pragma unroll
        for (int g = 0; g < 16; g++) {
            const unsigned sh = (unsigned)(g & 7) * 4u;
            float sv0 = fmaf(accL0[g], 0.0009765625f, accH0[g]);
            if (valid && (sv0 > best0[g])) {
                best0[g] = sv0;
                bkt0[g >> 3] = (bkt0[g >> 3] & ~(0xFu << sh)) | ((unsigned)kt << sh);
            }
            float sv1 = fmaf(accL1[g], 0.0009765625f, accH1[g]);
            if (valid && (sv1 > best1[g])) {
                best1[g] = sv1;
                bkt1[g >> 3] = (bkt1[g >> 3] & ~(0xFu << sh)) | ((unsigned)kt << sh);
            }
        }
    }

    // cross-lane argmax reduce within each 32-lane half, both n
    #pragma unroll
    for (int g = 0; g < 16; g++) {
        const int row = (g & 3) + 8 * (g >> 2) + 4 * khalf;
        const int mq = grp * 32 + row;               // packed row
        {
            float sv = best0[g];
            int kp = (int)((bkt0[g >> 3] >> ((g & 7) * 4)) & 0xFu) * 32 + lrow;
            for (int msk = 1; msk < 32; msk <<= 1) {
                float os = __shfl_xor(sv, msk, 64);
                int okp = __shfl_xor(kp, msk, 64);
                if (os > sv || (os == sv && okp < kp)) { sv = os; kp = okp; }
            }
            if (lrow == 0 && mq < QROWS) {
                bscore[(size_t)mq * 64 + n0] = sv;
                bidx[(size_t)mq * 64 + n0] = kp;
            }
        }
        {
            float sv = best1[g];
            int kp = (int)((bkt1[g >> 3] >> ((g & 7) * 4)) & 0xFu) * 32 + lrow;
            for (int msk = 1; msk < 32; msk <<= 1) {
                float os = __shfl_xor(sv, msk, 64);
                int okp = __shfl_xor(kp, msk, 64);
                if (os > sv || (os == sv && okp < kp)) { sv = os; kp = okp; }
            }
            if (lrow == 0 && mq < QROWS) {
                bscore[(size_t)mq * 64 + n0 + 1] = sv;
                bidx[(size_t)mq * 64 + n0 + 1] = kp;
            }
        }
    }
}

// ---------------- K4: softmax + gather-weight V + projection + fused mc conv ----------------
// R7: one block per packed row j (grid 1544 x 256), 4 waves split the 64-n
// gather 16 each (rs/idx via intra-wave shuffles), tree-sum in LDS, wave 0
// does projection + mc conv.
__global__ void k4_out(const float* __restrict__ query,
                       const float* __restrict__ qfeat, const float* __restrict__ vfeat,
                       const float* __restrict__ bscore, const int* __restrict__ bidx,
                       const float* __restrict__ q_scale,
                       const float* __restrict__ mw, const float* __restrict__ mb,
                       const float* __restrict__ mkey,
                       const float* __restrict__ ow, const float* __restrict__ ob,
                       float* __restrict__ out) {
    __shared__ float pS[4][128];
    const int t = threadIdx.x, wv = t >> 6, l = t & 63;
    const int j = blockIdx.x;                // 0..1543 packed row
    const int m = j / QN, qpos = j - m * QN;
    const int mq = m * QPAD + qpos;          // qfeat/q_scale layout

    float s = bscore[(size_t)j * 64 + l];
    int idx = bidx[(size_t)j * 64 + l];
    float msv = qfeat[(size_t)mq * 128 + l] * mkey[l]
              + qfeat[(size_t)mq * 128 + 64 + l] * mkey[64 + l];
    #pragma unroll
    for (int msk = 1; msk < 64; msk <<= 1) msv += __shfl_xor(msv, msk, 64);
    float mx = s;
    #pragma unroll
    for (int msk = 1; msk < 64; msk <<= 1) mx = fmaxf(mx, __shfl_xor(mx, msk, 64));
    mx = fmaxf(mx, msv);
    float e = expf(s - mx);
    float sum = e;
    #pragma unroll
    for (int msk = 1; msk < 64; msk <<= 1) sum += __shfl_xor(sum, msk, 64);
    float ems = expf(msv - mx);
    float inv = 1.f / (sum + ems);
    float rs = e * inv, msw = ems * inv;

    // wave wv gathers nn in [16*wv, 16*wv+16)
    float ax = 0.f, ay = 0.f;
    #pragma unroll
    for (int k = 0; k < 16; k++) {
        int nn = wv * 16 + k;
        float r = __shfl(rs, nn, 64);
        int  id = __shfl(idx, nn, 64);
        const float2 v = *(const float2*)&vfeat[((size_t)nn * KPAD + id) * 128 + 2 * l];
        ax = fmaf(r, v.x, ax);
        ay = fmaf(r, v.y, ay);
    }
    pS[wv][2 * l] = ax; pS[wv][2 * l + 1] = ay;
    __syncthreads();
    if (t < 128) pS[0][t] = (pS[0][t] + pS[1][t]) + (pS[2][t] + pS[3][t]);
    __syncthreads();
    if (wv == 0 && l < 32) {
        float p = 0.f;
        #pragma unroll
        for (int h4 = 0; h4 < 32; h4++) {
            const float4 wv4 = *(const float4*)&pS[0][h4 * 4];
            const float4 o4 = *(const float4*)&ow[l * 128 + h4 * 4];
            p += wv4.x * o4.x + wv4.y * o4.y + wv4.z * o4.z + wv4.w * o4.w;
        }
        p += (1.f - msw) * ob[l];
        // fused mc conv: mc[m, 32+qpos+l] = mb + sum_j mw[j]*query[m, tpos+j-63]
        float mcv = mb[0];
        const int tpos = 32 + qpos + l;
        for (int jj = 0; jj < 64; jj++) {
            int qi = tpos + jj - 63;
            if (qi >= 0) mcv = fmaf(mw[jj], query[m * 256 + qi], mcv);
        }
        float outv = q_scale[mq] * p + msw * mcv;
        out[(size_t)j * 32 + l] = outv;
    }
}

extern "C" void kernel_launch(void* const* d_in, const int* in_sizes, int n_in,
                              void* d_out, int out_size, void* d_ws, size_t ws_size,
                              hipStream_t stream) {
    const float* query = (const float*)d_in[0];
    const float* ref   = (const float*)d_in[1];
    const float* qw    = (const float*)d_in[2];
    const float* qb    = (const float*)d_in[3];
    const float* kw    = (const float*)d_in[4];
    const float* kb    = (const float*)d_in[5];
    const float* vw    = (const float*)d_in[6];
    const float* vb    = (const float*)d_in[7];
    const float* mw    = (const float*)d_in[8];
    const float* mb    = (const float*)d_in[9];
    const float* ow    = (const float*)d_in[10];
    const float* ob    = (const float*)d_in[11];
    const float* mkey  = (const float*)d_in[12];
    float* out = (float*)d_out;

    // workspace layout (floats), 16B-aligned; total 8128512 fl = 32.5 MB
    float* ws = (float*)d_ws;
    float* q_scale = ws;                          // 2048
    float* qfeat   = ws + 2048;                   // 262144 -> 264192
    float* bscore  = ws + 264192;                 // 131072 (uses 98816) -> 395264
    int*   bidx    = (int*)(ws + 395264);         // 131072 (uses 98816) -> 526336
    _Float16* qg   = (_Float16*)(ws + 526336);    // 524288 halfs -> 788480
    _Float16* kg   = (_Float16*)(ws + 788480);    // 7340032 halfs -> 4458496
    float* vfeat   = ws + 4458496;                // 3670016 -> 8128512

    hipLaunchKernelGGL(kA_feat, dim3(480), dim3(256), 0, stream,
                       query, ref, qw, qb, kw, kb, vw, vb,
                       q_scale, qfeat, qg, kg, vfeat);
    hipLaunchKernelGGL(k3_score, dim3(416), dim3(256), 0, stream,
                       qg, kg, bscore, bidx);
    hipLaunchKernelGGL(k4_out, dim3(1544), dim3(256), 0, stream,
                       query, qfeat, vfeat, bscore, bidx, q_scale, mw, mb, mkey, ow, ob, out);
}

// Round 12
// 182.343 us; speedup vs baseline: 1.1377x; 1.0918x over previous
//
#include <hip/hip_runtime.h>
#include <cmath>

// Problem constants
#define M_B   8
#define LQ    256
#define N_B   64
#define LR    512
#define COND  64
#define PRED  32
#define DH    128
#define QN    193      // LQ-COND+1
#define KN    417      // (LR-PRED)-COND+1
#define QPAD  256      // per-m padded q rows (qfeat/q_scale layout only)
#define KPAD  448      // padded kpos (14 chunks of 32)
#define QROWS 1544     // M_B*QN packed q rows (R7)
#define QGRPS 49       // ceil(QROWS/32)

typedef _Float16 half8 __attribute__((ext_vector_type(8)));
typedef float f32x16 __attribute__((ext_vector_type(16)));

__device__ __forceinline__ f32x16 mfma_f16(half8 a, half8 b, f32x16 c) {
    return __builtin_amdgcn_mfma_f32_32x32x16_f16(a, b, c, 0, 0, 0);
}
__device__ __forceinline__ f32x16 zero16() {
    f32x16 z;
    #pragma unroll
    for (int i = 0; i < 16; i++) z[i] = 0.f;
    return z;
}

#define GLOAD_LDS16(g, l) __builtin_amdgcn_global_load_lds( \
    (const __attribute__((address_space(1))) void*)(g), \
    (__attribute__((address_space(3))) void*)(l), 16, 0, 0)

// Force a float to live in a VGPR (blocks LDS-rematerialization of loads).
#define PIN_V(x) asm volatile("" : "+v"(x))

// ---------------- KA: fused feature kernel ----------------
// R6: scan-free (relative window sums, translation-invariant).
// R7: qg emitted in PACKED row layout (prow = m*QN + qpos, 49 groups of 32).
// R8/R9: no ghost memset (ghost rows provably inert).
// R12: Q-branch qc==0 blocks also precompute the mc conv (1792 distinct
// values mc[m,32..255]) into mcw — k4 was recomputing these 1544x on 32
// lanes with a serial 64-iter loop. Identical accumulation order ->
// bit-identical results.
__launch_bounds__(256, 2)
__global__ void kA_feat(const float* __restrict__ query, const float* __restrict__ ref,
                        const float* __restrict__ qw, const float* __restrict__ qb,
                        const float* __restrict__ kw, const float* __restrict__ kb,
                        const float* __restrict__ vw, const float* __restrict__ vb,
                        const float* __restrict__ mw, const float* __restrict__ mb,
                        float* __restrict__ q_scale, float* __restrict__ qfeat,
                        _Float16* __restrict__ qg,
                        _Float16* __restrict__ kg, float* __restrict__ vfeat,
                        float* __restrict__ mcw) {
    __shared__ float x[512];
    __shared__ float buf[128 * 65];
    const int t = threadIdx.x;
    const int kl = t & 63;
    const int hq = __builtin_amdgcn_readfirstlane(t >> 6);

    if (blockIdx.x < 448) {
        // ================= K/V branch =================
        const int n = blockIdx.x / 7, chunk = blockIdx.x % 7;
        x[t] = ref[n * 512 + t];
        x[t + 256] = ref[n * 512 + t + 256];
        __syncthreads();

        const int kp = chunk * 64 + kl;
        const bool vkp = kp < KN;
        // relative window sums: csw[j] = sum ref[kp+1 .. kp+j]  (csw[0] = 0)
        float csw[64];
        float run = 0.f, mn = 0.f, mx = 0.f;
        csw[0] = 0.f;
        #pragma unroll
        for (int j = 1; j < 64; j++) {
            run += x[kp + j];                // kp+63 <= 510, in range
            csw[j] = run;
            mn = fminf(mn, run);
            mx = fmaxf(mx, run);
        }
        float scv = mx - mn; if (scv == 0.f) scv = 1.f;
        const float inv = 1.f / scv;
        #pragma unroll
        for (int j = 0; j < 64; j++) { csw[j] -= mn; PIN_V(csw[j]); }

        // ---- k features ----
        for (int hh = 0; hh < 32; hh++) {
            const int h = hq * 32 + hh;      // wave-uniform -> s_load weights
            const float* wrow = kw + h * 64;
            float a0 = 0.f, a1 = 0.f, a2 = 0.f, a3 = 0.f;
            #pragma unroll
            for (int j = 0; j < 64; j += 4) {
                a0 = fmaf(wrow[j],     csw[j],     a0);
                a1 = fmaf(wrow[j + 1], csw[j + 1], a1);
                a2 = fmaf(wrow[j + 2], csw[j + 2], a2);
                a3 = fmaf(wrow[j + 3], csw[j + 3], a3);
            }
            float kraw = (a0 + a1) + (a2 + a3);
            float kval = vkp ? kraw * inv + kb[h] : 0.f;
            buf[h * 65 + (kl ^ (h >> 3))] = kval;
        }
        __syncthreads();
        // emit kg: 64 kp x 32 granules (16 hi + 16 lo), swizzled by kp&31
        {
            const size_t nb = ((size_t)n * KPAD + chunk * 64) * 256;
            #pragma unroll
            for (int r = 0; r < 8; r++) {
                int task = r * 256 + t;
                int kp_l = task >> 5, g = task & 31;
                int cb = g & 15, lo = g >> 4;
                half8 hv;
                #pragma unroll
                for (int jj = 0; jj < 8; jj++) {
                    float v = buf[(cb * 8 + jj) * 65 + (kp_l ^ cb)];
                    _Float16 hi = (_Float16)v;
                    hv[jj] = lo ? (_Float16)((v - (float)hi) * 1024.0f) : hi;
                }
                *(half8*)&kg[nb + (size_t)kp_l * 256 + ((size_t)(g ^ (kp_l & 31)) << 3)] = hv;
            }
        }
        __syncthreads();
        // ---- v features ----
        float refw[32];
        #pragma unroll
        for (int j = 0; j < 32; j++) {
            int ri = 64 + kp + j;
            refw[j] = (ri < 512) ? x[ri] : 0.f;
            PIN_V(refw[j]);
        }
        for (int hh = 0; hh < 32; hh++) {
            const int h = hq * 32 + hh;
            const float* vrow = vw + h * 32;
            float b0 = 0.f, b1 = 0.f;
            #pragma unroll
            for (int j = 0; j < 32; j += 2) {
                b0 = fmaf(vrow[j],     refw[j],     b0);
                b1 = fmaf(vrow[j + 1], refw[j + 1], b1);
            }
            float vval = vkp ? (b0 + b1) * inv + vb[h] : 0.f;
            buf[h * 65 + (kl ^ (h >> 3))] = vval;
        }
        __syncthreads();
        {
            const size_t vb0 = ((size_t)n * KPAD + chunk * 64) * 128;
            #pragma unroll
            for (int r = 0; r < 8; r++) {
                int idx = r * 256 + t;
                int kp_l = idx >> 5, c4 = idx & 31;
                float4 o;
                o.x = buf[(c4 * 4 + 0) * 65 + (kp_l ^ ((c4 * 4 + 0) >> 3))];
                o.y = buf[(c4 * 4 + 1) * 65 + (kp_l ^ ((c4 * 4 + 1) >> 3))];
                o.z = buf[(c4 * 4 + 2) * 65 + (kp_l ^ ((c4 * 4 + 2) >> 3))];
                o.w = buf[(c4 * 4 + 3) * 65 + (kp_l ^ ((c4 * 4 + 3) >> 3))];
                *(float4*)&vfeat[vb0 + (size_t)kp_l * 128 + c4 * 4] = o;
            }
        }
    } else {
        // ================= Q branch =================
        const int id = blockIdx.x - 448;
        const int m = id >> 2, qc = id & 3;
        x[t] = query[m * 256 + t];
        __syncthreads();

        // R12: mc precompute (qc==0 blocks; one thread per distinct value).
        // mc[m, 32+i] = mb + sum_jj mw[jj]*query[m, 32+i+jj-63], i in [0,224)
        if (qc == 0 && t < 224) {
            float mcv = mb[0];
            const int tpos = 32 + t;
            for (int jj = 0; jj < 64; jj++) {
                int qi = tpos + jj - 63;
                if (qi >= 0) mcv = fmaf(mw[jj], x[qi], mcv);
            }
            mcw[m * 224 + t] = mcv;
        }

        const int qpos = qc * 64 + kl;
        const bool vq = qpos < QN;
        const int base = vq ? qpos : (QN - 1);
        float csw[64];
        float run = 0.f, mn = 0.f, mx = 0.f;
        csw[0] = 0.f;
        #pragma unroll
        for (int j = 1; j < 64; j++) {
            run += x[base + j];              // base+63 <= 255, in range
            csw[j] = run;
            mn = fminf(mn, run);
            mx = fmaxf(mx, run);
        }
        float sc = mx - mn; if (sc == 0.f) sc = 1.f;
        const float inv = 1.f / sc;
        if (t < 64) q_scale[m * QPAD + qpos] = vq ? sc : 1.f;
        #pragma unroll
        for (int j = 0; j < 64; j++) { csw[j] -= mn; PIN_V(csw[j]); }

        for (int hh = 0; hh < 32; hh++) {
            const int h = hq * 32 + hh;      // wave-uniform -> s_load weights
            const float* wrow = qw + h * 64;
            float a0 = 0.f, a1 = 0.f, a2 = 0.f, a3 = 0.f;
            #pragma unroll
            for (int j = 0; j < 64; j += 4) {
                a0 = fmaf(wrow[j],     csw[j],     a0);
                a1 = fmaf(wrow[j + 1], csw[j + 1], a1);
                a2 = fmaf(wrow[j + 2], csw[j + 2], a2);
                a3 = fmaf(wrow[j + 3], csw[j + 3], a3);
            }
            float raw = (a0 + a1) + (a2 + a3);
            float val = vq ? raw * inv + qb[h] : 0.f;
            buf[h * 65 + (kl ^ (h >> 3))] = val;
        }
        __syncthreads();
        // emit qfeat (coalesced float4, QPAD layout — unchanged)
        const size_t qb0 = ((size_t)m * QPAD + qc * 64) * 128;
        #pragma unroll
        for (int r = 0; r < 8; r++) {
            int idx = r * 256 + t;
            int qp_l = idx >> 5, c4 = idx & 31;
            float4 o;
            o.x = buf[(c4 * 4 + 0) * 65 + (qp_l ^ ((c4 * 4 + 0) >> 3))];
            o.y = buf[(c4 * 4 + 1) * 65 + (qp_l ^ ((c4 * 4 + 1) >> 3))];
            o.z = buf[(c4 * 4 + 2) * 65 + (qp_l ^ ((c4 * 4 + 2) >> 3))];
            o.w = buf[(c4 * 4 + 3) * 65 + (qp_l ^ ((c4 * 4 + 3) >> 3))];
            *(float4*)&qfeat[qb0 + (size_t)qp_l * 128 + c4 * 4] = o;
        }
        // emit qg frag-major hi/lo, PACKED rows: prow = m*QN + qpos
        #pragma unroll
        for (int r = 0; r < 8; r++) {
            int idx = r * 256 + t;
            int qp_l = idx >> 5, g = idx & 31;
            int c = g >> 2, kh = (g >> 1) & 1, lo = g & 1;
            int qp2 = qc * 64 + qp_l;
            if (qp2 < QN) {
                half8 hv;
                #pragma unroll
                for (int jj = 0; jj < 8; jj++) {
                    int h = c * 16 + kh * 8 + jj;
                    float v = buf[h * 65 + (qp_l ^ (h >> 3))];
                    _Float16 hi = (_Float16)v;
                    hv[jj] = lo ? (_Float16)((v - (float)hi) * 1024.0f) : hi;
                }
                int prow = m * QN + qp2;
                int grp = prow >> 5;
                size_t fb = (size_t)(grp * 16 + c * 2 + lo);
                *(half8*)&qg[fb * 512 + (size_t)(kh * 32 + (prow & 31)) * 8] = hv;
            }
        }
    }
}

// ---------------- K3: split-f16 MFMA score matmul + max/argmax ----------------
// R9 exact (known-best 56.0 us): single-n, grid 832 = qt(13) x n(64), LDS
// double-buffered global_load_lds staging, two accumulators accH/accL.
// Exploration ledger (all tested, all >= this): occupancy variants (R3/R4),
// split-K (R3), direct-global (R5, +35%), 3-chain dep-split (R8, spill),
// 2-n amortization (R10, +7%). Structural floor at 2-wave MFMA issue; pure
// MFMA floor ~15.4 us (1.12M MFMA x 34cy / 1024 SIMD).
__launch_bounds__(256, 3)
__global__ void k3_score(const _Float16* __restrict__ qg, const _Float16* __restrict__ kg,
                         float* __restrict__ bscore, int* __restrict__ bidx) {
    __shared__ _Float16 Kbuf[2][32 * 256];   // 16 KB each
    const int blk = blockIdx.x;
    const int n = blk & 63, qt = blk >> 6;   // qt in [0,13)
    const int t = threadIdx.x, w = t >> 6, l = t & 63;
    const int lrow = l & 31, khalf = l >> 5;

    // Q fragments: one 32-row group per wave, [c=8][hi/lo]
    const int grp = qt * 4 + w;              // group in [0,52); >=49 are ghosts
    half8 qf[8][2];
    #pragma unroll
    for (int c = 0; c < 8; c++)
        #pragma unroll
        for (int h = 0; h < 2; h++)
            qf[c][h] = ((const half8*)qg)[(size_t)(grp * 16 + c * 2 + h) * 64 + l];

    const _Float16* ksrc = kg + (size_t)n * KPAD * 256;

    float best[16];
    int bestkt[16];
    #pragma unroll
    for (int g = 0; g < 16; g++) { best[g] = -INFINITY; bestkt[g] = 0; }

    // stage chunk 0 (16 KB): wave-uniform base + lane*16
    #pragma unroll
    for (int rd = 0; rd < 4; rd++) {
        int e = (rd * 4 + w) * 512 + l * 8;
        GLOAD_LDS16(ksrc + e, &Kbuf[0][0] + e);
    }

    for (int kt = 0; kt < 14; kt++) {
        __syncthreads();                       // drains vmcnt -> chunk kt ready
        if (kt < 13) {
            const _Float16* src = ksrc + (size_t)(kt + 1) * (32 * 256);
            _Float16* dst = &Kbuf[(kt + 1) & 1][0];
            #pragma unroll
            for (int rd = 0; rd < 4; rd++) {
                int e = (rd * 4 + w) * 512 + l * 8;
                GLOAD_LDS16(src + e, dst + e);
            }
        }
        const _Float16* krow = &Kbuf[kt & 1][0] + lrow * 256;
        f32x16 accH = zero16(), accL = zero16();
        // software-pipelined B-frag reads: c+1 issued before c's MFMAs
        half8 bh = *(const half8*)(krow + ((khalf ^ lrow) * 8));
        half8 bl = *(const half8*)(krow + (((16 + khalf) ^ lrow) * 8));
        #pragma unroll
        for (int c = 0; c < 8; c++) {
            half8 nbh, nbl;
            if (c < 7) {
                nbh = *(const half8*)(krow + ((((c + 1) * 2 + khalf) ^ lrow) * 8));
                nbl = *(const half8*)(krow + (((16 + (c + 1) * 2 + khalf) ^ lrow) * 8));
            }
            accH = mfma_f16(qf[c][0], bh, accH);
            accL = mfma_f16(qf[c][0], bl, accL);
            accL = mfma_f16(qf[c][1], bh, accL);
            bh = nbh; bl = nbl;
        }
        const int kp = kt * 32 + lrow;
        const bool valid = kp < KN;
        #pragma unroll
        for (int g = 0; g < 16; g++) {
            float sv = fmaf(accL[g], 0.0009765625f, accH[g]);
            // strict > with ascending kp => numpy first-index tie-break per lane
            if (valid && (sv > best[g])) { best[g] = sv; bestkt[g] = kt; }
        }
    }

    // cross-lane argmax reduce within each 32-lane half
    #pragma unroll
    for (int g = 0; g < 16; g++) {
        float sv = best[g];
        int kp = bestkt[g] * 32 + lrow;
        for (int msk = 1; msk < 32; msk <<= 1) {
            float os = __shfl_xor(sv, msk, 64);
            int okp = __shfl_xor(kp, msk, 64);
            if (os > sv || (os == sv && okp < kp)) { sv = os; kp = okp; }
        }
        if (lrow == 0) {
            int row = (g & 3) + 8 * (g >> 2) + 4 * khalf;
            int mq = grp * 32 + row;               // packed row
            if (mq < QROWS) {
                bscore[(size_t)mq * 64 + n] = sv;
                bidx[(size_t)mq * 64 + n] = kp;
            }
        }
    }
}

// ---------------- K4: softmax + gather-weight V + projection ----------------
// R7: one block per packed row j (grid 1544 x 256), 4 waves split the 64-n
// gather 16 each, tree-sum in LDS, wave 0 does projection.
// R12: mc conv replaced by one load from mcw (precomputed in kA).
__global__ void k4_out(const float* __restrict__ mcw,
                       const float* __restrict__ qfeat, const float* __restrict__ vfeat,
                       const float* __restrict__ bscore, const int* __restrict__ bidx,
                       const float* __restrict__ q_scale,
                       const float* __restrict__ mkey,
                       const float* __restrict__ ow, const float* __restrict__ ob,
                       float* __restrict__ out) {
    __shared__ float pS[4][128];
    const int t = threadIdx.x, wv = t >> 6, l = t & 63;
    const int j = blockIdx.x;                // 0..1543 packed row
    const int m = j / QN, qpos = j - m * QN;
    const int mq = m * QPAD + qpos;          // qfeat/q_scale layout

    float s = bscore[(size_t)j * 64 + l];
    int idx = bidx[(size_t)j * 64 + l];
    float msv = qfeat[(size_t)mq * 128 + l] * mkey[l]
              + qfeat[(size_t)mq * 128 + 64 + l] * mkey[64 + l];
    #pragma unroll
    for (int msk = 1; msk < 64; msk <<= 1) msv += __shfl_xor(msv, msk, 64);
    float mx = s;
    #pragma unroll
    for (int msk = 1; msk < 64; msk <<= 1) mx = fmaxf(mx, __shfl_xor(mx, msk, 64));
    mx = fmaxf(mx, msv);
    float e = expf(s - mx);
    float sum = e;
    #pragma unroll
    for (int msk = 1; msk < 64; msk <<= 1) sum += __shfl_xor(sum, msk, 64);
    float ems = expf(msv - mx);
    float inv = 1.f / (sum + ems);
    float rs = e * inv, msw = ems * inv;

    // wave wv gathers nn in [16*wv, 16*wv+16)
    float ax = 0.f, ay = 0.f;
    #pragma unroll
    for (int k = 0; k < 16; k++) {
        int nn = wv * 16 + k;
        float r = __shfl(rs, nn, 64);
        int  id = __shfl(idx, nn, 64);
        const float2 v = *(const float2*)&vfeat[((size_t)nn * KPAD + id) * 128 + 2 * l];
        ax = fmaf(r, v.x, ax);
        ay = fmaf(r, v.y, ay);
    }
    pS[wv][2 * l] = ax; pS[wv][2 * l + 1] = ay;
    __syncthreads();
    if (t < 128) pS[0][t] = (pS[0][t] + pS[1][t]) + (pS[2][t] + pS[3][t]);
    __syncthreads();
    if (wv == 0 && l < 32) {
        float p = 0.f;
        #pragma unroll
        for (int h4 = 0; h4 < 32; h4++) {
            const float4 wv4 = *(const float4*)&pS[0][h4 * 4];
            const float4 o4 = *(const float4*)&ow[l * 128 + h4 * 4];
            p += wv4.x * o4.x + wv4.y * o4.y + wv4.z * o4.z + wv4.w * o4.w;
        }
        p += (1.f - msw) * ob[l];
        // R12: mc loaded from kA's precompute (bit-identical accumulation)
        float mcv = mcw[m * 224 + qpos + l];
        float outv = q_scale[mq] * p + msw * mcv;
        out[(size_t)j * 32 + l] = outv;
    }
}

extern "C" void kernel_launch(void* const* d_in, const int* in_sizes, int n_in,
                              void* d_out, int out_size, void* d_ws, size_t ws_size,
                              hipStream_t stream) {
    const float* query = (const float*)d_in[0];
    const float* ref   = (const float*)d_in[1];
    const float* qw    = (const float*)d_in[2];
    const float* qb    = (const float*)d_in[3];
    const float* kw    = (const float*)d_in[4];
    const float* kb    = (const float*)d_in[5];
    const float* vw    = (const float*)d_in[6];
    const float* vb    = (const float*)d_in[7];
    const float* mw    = (const float*)d_in[8];
    const float* mb    = (const float*)d_in[9];
    const float* ow    = (const float*)d_in[10];
    const float* ob    = (const float*)d_in[11];
    const float* mkey  = (const float*)d_in[12];
    float* out = (float*)d_out;

    // workspace layout (floats), 16B-aligned; total 8128512 fl = 32.5 MB
    float* ws = (float*)d_ws;
    float* q_scale = ws;                          // 2048
    float* qfeat   = ws + 2048;                   // 262144 -> 264192
    float* bscore  = ws + 264192;                 // uses 98816 of 131072 -> 395264
    float* mcw     = ws + 363008;                 // 1792 fl in bscore slack
    int*   bidx    = (int*)(ws + 395264);         // uses 98816 of 131072 -> 526336
    _Float16* qg   = (_Float16*)(ws + 526336);    // 524288 halfs -> 788480
    _Float16* kg   = (_Float16*)(ws + 788480);    // 7340032 halfs -> 4458496
    float* vfeat   = ws + 4458496;                // 3670016 -> 8128512

    hipLaunchKernelGGL(kA_feat, dim3(480), dim3(256), 0, stream,
                       query, ref, qw, qb, kw, kb, vw, vb, mw, mb,
                       q_scale, qfeat, qg, kg, vfeat, mcw);
    hipLaunchKernelGGL(k3_score, dim3(832), dim3(256), 0, stream,
                       qg, kg, bscore, bidx);
    hipLaunchKernelGGL(k4_out, dim3(1544), dim3(256), 0, stream,
                       mcw, qfeat, vfeat, bscore, bidx, q_scale, mkey, ow, ob, out);
}